// Round 1
// baseline (134.616 us; speedup 1.0000x reference)
//
#include <hip/hip_runtime.h>

// SSIM loss, fused separable depthwise Gaussian conv (11x11, sigma=1.5).
// Input: X, Y fp32 (16,3,512,512). Output: scalar 1 - mean(ssim_map).

#define OH 32          // output tile rows per block
#define OW 32          // output tile cols per block
#define IH (OH + 10)   // halo tile rows (42)
#define IW (OW + 10)   // halo tile cols (42)
#define TILES_R 16     // 512/32
#define TILES_C 16
#define NIMG 48        // 16*3
#define NBLOCKS (NIMG * TILES_R * TILES_C)  // 12288
#define NPIXEL 12582912.0                   // 16*3*512*512

__global__ __launch_bounds__(256) void ssim_tile_kernel(
    const float* __restrict__ X, const float* __restrict__ Y,
    float* __restrict__ partial)
{
    __shared__ float sX[IH][IW + 1];   // +1 pad
    __shared__ float sY[IH][IW + 1];
    __shared__ float hb[5][IH][OW];    // horizontal conv results: x, y, xx, yy, xy

    const int bid = blockIdx.x;
    const int img = bid >> 8;          // / (TILES_R*TILES_C)
    const int rem = bid & 255;
    const int tr  = rem >> 4;
    const int tc  = rem & 15;
    const int tid = threadIdx.x;

    const float* __restrict__ Xi = X + (size_t)img * (512 * 512);
    const float* __restrict__ Yi = Y + (size_t)img * (512 * 512);

    // Gaussian weights (matches jnp: exp(-(i-5)^2 / (2*1.5^2)), normalized)
    float g[11];
    {
        float s = 0.f;
        #pragma unroll
        for (int i = 0; i < 11; ++i) {
            float d = (float)(i - 5);
            float e = expf(-d * d * (1.0f / 4.5f));
            g[i] = e; s += e;
        }
        float inv = 1.0f / s;
        #pragma unroll
        for (int i = 0; i < 11; ++i) g[i] *= inv;
    }

    const int r0 = tr * OH - 5;
    const int c0 = tc * OW - 5;

    // ---- stage halo tile (zero padding outside image) ----
    for (int p = tid; p < IH * IW; p += 256) {
        int r = p / IW;
        int c = p - r * IW;
        int gr = r0 + r, gc = c0 + c;
        float xv = 0.f, yv = 0.f;
        if ((unsigned)gr < 512u && (unsigned)gc < 512u) {
            size_t off = (size_t)gr * 512 + (size_t)gc;
            xv = Xi[off]; yv = Yi[off];
        }
        sX[r][c] = xv;
        sY[r][c] = yv;
    }
    __syncthreads();

    // ---- horizontal 11-tap pass over 5 maps ----
    for (int p = tid; p < IH * OW; p += 256) {
        int r = p >> 5;       // OW == 32
        int c = p & 31;
        float hx = 0.f, hy = 0.f, hxx = 0.f, hyy = 0.f, hxy = 0.f;
        #pragma unroll
        for (int k = 0; k < 11; ++k) {
            float x = sX[r][c + k];
            float y = sY[r][c + k];
            float w = g[k];
            float wx = w * x, wy = w * y;
            hx += wx;
            hy += wy;
            hxx = fmaf(wx, x, hxx);
            hyy = fmaf(wy, y, hyy);
            hxy = fmaf(wx, y, hxy);
        }
        hb[0][r][c] = hx;
        hb[1][r][c] = hy;
        hb[2][r][c] = hxx;
        hb[3][r][c] = hyy;
        hb[4][r][c] = hxy;
    }
    __syncthreads();

    // ---- vertical 11-tap pass + SSIM formula ----
    float lsum = 0.f;
    for (int p = tid; p < OH * OW; p += 256) {
        int r = p >> 5;
        int c = p & 31;
        float mu1 = 0.f, mu2 = 0.f, vxx = 0.f, vyy = 0.f, vxy = 0.f;
        #pragma unroll
        for (int k = 0; k < 11; ++k) {
            float w = g[k];
            mu1 = fmaf(w, hb[0][r + k][c], mu1);
            mu2 = fmaf(w, hb[1][r + k][c], mu2);
            vxx = fmaf(w, hb[2][r + k][c], vxx);
            vyy = fmaf(w, hb[3][r + k][c], vyy);
            vxy = fmaf(w, hb[4][r + k][c], vxy);
        }
        float m11 = mu1 * mu1, m22 = mu2 * mu2, m12 = mu1 * mu2;
        float s1 = vxx - m11, s2 = vyy - m22, s12 = vxy - m12;
        const float C1 = 1e-4f;   // (0.01*1)^2
        const float C2 = 9e-4f;   // (0.03*1)^2
        float num = (2.f * m12 + C1) * (2.f * s12 + C2);
        float den = (m11 + m22 + C1) * (s1 + s2 + C2);
        lsum += num / den;
    }

    // ---- block reduction (wave shuffle + LDS across 4 waves) ----
    #pragma unroll
    for (int off = 32; off > 0; off >>= 1)
        lsum += __shfl_down(lsum, off, 64);

    __shared__ float wsum[4];
    const int lane = tid & 63, wid = tid >> 6;
    if (lane == 0) wsum[wid] = lsum;
    __syncthreads();
    if (tid == 0)
        partial[bid] = wsum[0] + wsum[1] + wsum[2] + wsum[3];
}

__global__ __launch_bounds__(256) void ssim_reduce_kernel(
    const float* __restrict__ partial, float* __restrict__ out)
{
    const int tid = threadIdx.x;
    double s = 0.0;
    for (int i = tid; i < NBLOCKS; i += 256) s += (double)partial[i];
    __shared__ double sd[256];
    sd[tid] = s;
    __syncthreads();
    for (int off = 128; off > 0; off >>= 1) {
        if (tid < off) sd[tid] += sd[tid + off];
        __syncthreads();
    }
    if (tid == 0) out[0] = (float)(1.0 - sd[0] / NPIXEL);
}

extern "C" void kernel_launch(void* const* d_in, const int* in_sizes, int n_in,
                              void* d_out, int out_size, void* d_ws, size_t ws_size,
                              hipStream_t stream) {
    const float* X = (const float*)d_in[0];
    const float* Y = (const float*)d_in[1];
    float* partial = (float*)d_ws;     // NBLOCKS floats = 48 KiB
    float* out = (float*)d_out;

    ssim_tile_kernel<<<NBLOCKS, 256, 0, stream>>>(X, Y, partial);
    ssim_reduce_kernel<<<1, 256, 0, stream>>>(partial, out);
}

// Round 2
// 70.835 us; speedup vs baseline: 1.9004x; 1.9004x over previous
//
#include <hip/hip_runtime.h>

// SSIM loss via separable Gaussian conv (11 taps, sigma=1.5), row-sweep
// register-ring structure: h-pass once per input row into a 5x11 register
// ring per thread (one column each); v-pass entirely from registers.

#define ROWS 32                 // output rows per band
#define COLS 256                // output cols per band (== blockDim)
#define NI   (ROWS + 10)        // 42 input rows per band
#define LW   (COLS + 10)        // 266-wide staged row
#define NIMG 48
#define NBLOCKS (NIMG * 2 * 16) // 1536
#define NPIXEL 12582912.0       // 16*3*512*512

__global__ __launch_bounds__(256) void ssim_row_kernel(
    const float* __restrict__ X, const float* __restrict__ Y,
    float* __restrict__ partial)
{
    __shared__ float sb[2][2][LW + 6];   // [dbuf][x/y][col]

    const int tid = threadIdx.x;
    const int bid = blockIdx.x;
    const int img = bid >> 5;
    const int rem = bid & 31;
    const int c0  = (rem & 1) * COLS;
    const int r0  = (rem >> 1) * ROWS;

    const float* __restrict__ Xi = X + (size_t)img * (512 * 512);
    const float* __restrict__ Yi = Y + (size_t)img * (512 * 512);

    // Gaussian weights (matches jnp construction)
    float g[11];
    {
        float s = 0.f;
        #pragma unroll
        for (int i = 0; i < 11; ++i) {
            float d = (float)(i - 5);
            float e = expf(-d * d * (1.0f / 4.5f));
            g[i] = e; s += e;
        }
        float inv = 1.0f / s;
        #pragma unroll
        for (int i = 0; i < 11; ++i) g[i] *= inv;
    }

    const bool tail = (tid < LW - COLS);   // tid < 10 loads the right edge
    const int  gc0  = c0 - 5 + tid;
    const int  gc1  = gc0 + COLS;

    // ---- prologue: stage input row j=0 into buffer 0 ----
    {
        int gr = r0 - 5;
        float x0 = 0.f, y0 = 0.f, x1 = 0.f, y1 = 0.f;
        if ((unsigned)gr < 512u) {
            const float* xr = Xi + (size_t)gr * 512;
            const float* yr = Yi + (size_t)gr * 512;
            if ((unsigned)gc0 < 512u) { x0 = xr[gc0]; y0 = yr[gc0]; }
            if (tail && (unsigned)gc1 < 512u) { x1 = xr[gc1]; y1 = yr[gc1]; }
        }
        sb[0][0][tid] = x0; sb[0][1][tid] = y0;
        if (tail) { sb[0][0][tid + COLS] = x1; sb[0][1][tid + COLS] = y1; }
    }
    __syncthreads();

    float ring[5][11];   // x, y, xx, yy, xy  — static-indexed only
    float acc = 0.f;

    const float C1 = 1e-4f, C2 = 9e-4f;

    #pragma unroll 1
    for (int jb = 0; jb < 44; jb += 11) {      // outer rolled: protect I-cache
        #pragma unroll
        for (int ph = 0; ph < 11; ++ph) {      // inner unrolled: static ring idx
            int j = jb + ph;                   // j % 11 == ph  (jb % 11 == 0)
            if (j < NI) {
                const int cur = j & 1, nxt = cur ^ 1;
                const int jn = j + 1;

                // --- issue next-row global loads early (hide HBM latency) ---
                float nx0 = 0.f, ny0 = 0.f, nx1 = 0.f, ny1 = 0.f;
                if (jn < NI) {
                    int gr = r0 - 5 + jn;
                    if ((unsigned)gr < 512u) {
                        const float* xr = Xi + (size_t)gr * 512;
                        const float* yr = Yi + (size_t)gr * 512;
                        if ((unsigned)gc0 < 512u) { nx0 = xr[gc0]; ny0 = yr[gc0]; }
                        if (tail && (unsigned)gc1 < 512u) { nx1 = xr[gc1]; ny1 = yr[gc1]; }
                    }
                }

                // --- h-pass on row j from sb[cur]; push into ring slot ph ---
                {
                    float hx = 0.f, hy = 0.f, hxx = 0.f, hyy = 0.f, hxy = 0.f;
                    #pragma unroll
                    for (int k = 0; k < 11; ++k) {
                        float x = sb[cur][0][tid + k];
                        float y = sb[cur][1][tid + k];
                        float w = g[k];
                        float wx = w * x, wy = w * y;
                        hx += wx; hy += wy;
                        hxx = fmaf(wx, x, hxx);
                        hyy = fmaf(wy, y, hyy);
                        hxy = fmaf(wx, y, hxy);
                    }
                    ring[0][ph] = hx;  ring[1][ph] = hy;
                    ring[2][ph] = hxx; ring[3][ph] = hyy; ring[4][ph] = hxy;
                }

                // --- v-pass from ring: output row j-10..  (valid once j>=10) ---
                if (j >= 10) {
                    float mu1 = 0.f, mu2 = 0.f, vxx = 0.f, vyy = 0.f, vxy = 0.f;
                    #pragma unroll
                    for (int k = 0; k < 11; ++k) {
                        const int s = (ph + 1 + k) % 11;  // slot of h-row j-10+k
                        float w = g[k];
                        mu1 = fmaf(w, ring[0][s], mu1);
                        mu2 = fmaf(w, ring[1][s], mu2);
                        vxx = fmaf(w, ring[2][s], vxx);
                        vyy = fmaf(w, ring[3][s], vyy);
                        vxy = fmaf(w, ring[4][s], vxy);
                    }
                    float m11 = mu1 * mu1, m22 = mu2 * mu2, m12 = mu1 * mu2;
                    float s1 = vxx - m11, s2 = vyy - m22, s12 = vxy - m12;
                    float num = (2.f * m12 + C1) * (2.f * s12 + C2);
                    float den = (m11 + m22 + C1) * (s1 + s2 + C2);
                    acc = fmaf(num, __builtin_amdgcn_rcpf(den), acc);
                }

                // --- write next row into the other buffer, then sync ---
                if (jn < NI) {
                    sb[nxt][0][tid] = nx0; sb[nxt][1][tid] = ny0;
                    if (tail) { sb[nxt][0][tid + COLS] = nx1; sb[nxt][1][tid + COLS] = ny1; }
                }
                __syncthreads();
            }
        }
    }

    // ---- block reduction ----
    #pragma unroll
    for (int off = 32; off > 0; off >>= 1)
        acc += __shfl_down(acc, off, 64);

    __shared__ float wsum[4];
    const int lane = tid & 63, wid = tid >> 6;
    if (lane == 0) wsum[wid] = acc;
    __syncthreads();
    if (tid == 0)
        partial[bid] = wsum[0] + wsum[1] + wsum[2] + wsum[3];
}

__global__ __launch_bounds__(256) void ssim_reduce_kernel(
    const float* __restrict__ partial, float* __restrict__ out)
{
    const int tid = threadIdx.x;
    double s = 0.0;
    for (int i = tid; i < NBLOCKS; i += 256) s += (double)partial[i];
    __shared__ double sd[256];
    sd[tid] = s;
    __syncthreads();
    for (int off = 128; off > 0; off >>= 1) {
        if (tid < off) sd[tid] += sd[tid + off];
        __syncthreads();
    }
    if (tid == 0) out[0] = (float)(1.0 - sd[0] / NPIXEL);
}

extern "C" void kernel_launch(void* const* d_in, const int* in_sizes, int n_in,
                              void* d_out, int out_size, void* d_ws, size_t ws_size,
                              hipStream_t stream) {
    const float* X = (const float*)d_in[0];
    const float* Y = (const float*)d_in[1];
    float* partial = (float*)d_ws;   // NBLOCKS floats = 6 KiB
    float* out = (float*)d_out;

    ssim_row_kernel<<<NBLOCKS, 256, 0, stream>>>(X, Y, partial);
    ssim_reduce_kernel<<<1, 256, 0, stream>>>(partial, out);
}

// Round 3
// 63.816 us; speedup vs baseline: 2.1094x; 1.1100x over previous
//
#include <hip/hip_runtime.h>
#include <hip/hip_fp16.h>

// SSIM loss, separable 11-tap Gaussian (sigma=1.5), packed-f16 row sweep.
// Each thread owns 2 adjacent columns (one __half2 lane-pair); block covers a
// full 512-wide row band. h-pass from LDS pair-dwords (even/odd split arrays,
// stride-1 conflict-free), 5x11 __half2 register ring, v-pass from registers,
// SSIM formula in f32.

#define ROWS 32                  // output rows per band
#define NI   (ROWS + 10)         // 42 input rows per band
#define NBLOCKS (48 * 16)        // 768: 48 images x 16 row bands
#define NPIXEL 12582912.0        // 16*3*512*512

__global__ __launch_bounds__(256) void ssim_pk_kernel(
    const float* __restrict__ X, const float* __restrict__ Y,
    float* __restrict__ partial)
{
    // sb[dbuf][map x/y][E=0,O=1][262]; dword[2j] = E[j+3], dword[2j+1] = O[j+3]
    __shared__ __half2 sb[2][2][2][262];

    const int tid = threadIdx.x;
    const int bid = blockIdx.x;
    const int img = bid >> 4;
    const int r0  = (bid & 15) * ROWS;

    const float* __restrict__ Xi = X + (size_t)img * (512 * 512);
    const float* __restrict__ Yi = Y + (size_t)img * (512 * 512);

    // Gaussian weights (f32 build matches jnp), broadcast to half2
    float g[11];
    {
        float s = 0.f;
        #pragma unroll
        for (int i = 0; i < 11; ++i) {
            float d = (float)(i - 5);
            float e = expf(-d * d * (1.0f / 4.5f));
            g[i] = e; s += e;
        }
        float inv = 1.0f / s;
        #pragma unroll
        for (int i = 0; i < 11; ++i) g[i] *= inv;
    }
    __half2 w2[11];
    #pragma unroll
    for (int i = 0; i < 11; ++i) w2[i] = __float2half2_rn(g[i]);

    const __half2 hz = __float2half2_rn(0.f);

    // ---- one-time edge zero-fill (both buffers, both maps) ----
    if (tid < 2) {
        #pragma unroll
        for (int b = 0; b < 2; ++b)
            #pragma unroll
            for (int m = 0; m < 2; ++m) {
                sb[b][m][0][1 + tid]   = hz;   // E idx 1,2      (dword -4,-2)
                sb[b][m][0][259 + tid] = hz;   // E idx 259,260  (dword 512,514)
                sb[b][m][1][tid]       = hz;   // O idx 0,1      (dword -5,-3)
                sb[b][m][1][259 + tid] = hz;   // O idx 259,260  (dword 513,515)
            }
    }

    const int c2 = 2 * tid;

    // ---- stage row j=0 into buffer 0 ----
    {
        int gr = r0 - 5;
        float2 xv = {0.f, 0.f}, yv = {0.f, 0.f};
        float xn = 0.f, yn = 0.f;
        if ((unsigned)gr < 512u) {
            const float* xr = Xi + (size_t)gr * 512;
            const float* yr = Yi + (size_t)gr * 512;
            xv = *(const float2*)(xr + c2);
            yv = *(const float2*)(yr + c2);
            if (tid < 255) { xn = xr[c2 + 2]; yn = yr[c2 + 2]; }
        }
        sb[0][0][0][tid + 3] = __floats2half2_rn(xv.x, xv.y);
        sb[0][0][1][tid + 3] = __floats2half2_rn(xv.y, xn);
        sb[0][1][0][tid + 3] = __floats2half2_rn(yv.x, yv.y);
        sb[0][1][1][tid + 3] = __floats2half2_rn(yv.y, yn);
        if (tid == 0) {   // dword[-1] = (0, x[0]) -> O idx 2
            sb[0][0][1][2] = __floats2half2_rn(0.f, xv.x);
            sb[0][1][1][2] = __floats2half2_rn(0.f, yv.x);
        }
    }
    __syncthreads();

    __half2 ring[5][11];   // x, y, xx, yy, xy — static indices only
    float acc = 0.f;
    const float C1 = 1e-4f, C2 = 9e-4f;

    #pragma unroll 1
    for (int jb = 0; jb < 44; jb += 11) {
        #pragma unroll
        for (int ph = 0; ph < 11; ++ph) {
            int j = jb + ph;                  // j % 11 == ph
            if (j < NI) {
                const int cur = j & 1, nxt = cur ^ 1;
                const int jn = j + 1;

                // --- issue next-row global loads early ---
                float2 nxv = {0.f, 0.f}, nyv = {0.f, 0.f};
                float nxn = 0.f, nyn = 0.f;
                if (jn < NI) {
                    int gr = r0 - 5 + jn;
                    if ((unsigned)gr < 512u) {
                        const float* xr = Xi + (size_t)gr * 512;
                        const float* yr = Yi + (size_t)gr * 512;
                        nxv = *(const float2*)(xr + c2);
                        nyv = *(const float2*)(yr + c2);
                        if (tid < 255) { nxn = xr[c2 + 2]; nyn = yr[c2 + 2]; }
                    }
                }

                // --- h-pass (packed, 2 cols) from conflict-free E/O arrays ---
                {
                    const __half2* ex = &sb[cur][0][0][tid];
                    const __half2* ox = &sb[cur][0][1][tid];
                    const __half2* ey = &sb[cur][1][0][tid];
                    const __half2* oy = &sb[cur][1][1][tid];
                    __half2 hx = hz, hy = hz, hxx = hz, hyy = hz, hxy = hz;
                    #pragma unroll
                    for (int k = 0; k < 11; ++k) {
                        __half2 xk = (k & 1) ? ex[(k + 1) >> 1] : ox[k >> 1];
                        __half2 yk = (k & 1) ? ey[(k + 1) >> 1] : oy[k >> 1];
                        __half2 wx = __hmul2(w2[k], xk);
                        __half2 wy = __hmul2(w2[k], yk);
                        hx  = __hadd2(hx, wx);
                        hy  = __hadd2(hy, wy);
                        hxx = __hfma2(wx, xk, hxx);
                        hyy = __hfma2(wy, yk, hyy);
                        hxy = __hfma2(wx, yk, hxy);
                    }
                    ring[0][ph] = hx;  ring[1][ph] = hy;
                    ring[2][ph] = hxx; ring[3][ph] = hyy; ring[4][ph] = hxy;
                }

                // --- v-pass from ring (valid once j >= 10) ---
                if (j >= 10) {
                    __half2 mu1 = hz, mu2 = hz, vxx = hz, vyy = hz, vxy = hz;
                    #pragma unroll
                    for (int k = 0; k < 11; ++k) {
                        const int s = (ph + 1 + k) % 11;
                        mu1 = __hfma2(w2[k], ring[0][s], mu1);
                        mu2 = __hfma2(w2[k], ring[1][s], mu2);
                        vxx = __hfma2(w2[k], ring[2][s], vxx);
                        vyy = __hfma2(w2[k], ring[3][s], vyy);
                        vxy = __hfma2(w2[k], ring[4][s], vxy);
                    }
                    float2 m1 = __half22float2(mu1);
                    float2 m2 = __half22float2(mu2);
                    float2 xx = __half22float2(vxx);
                    float2 yy = __half22float2(vyy);
                    float2 xy = __half22float2(vxy);
                    #pragma unroll
                    for (int h = 0; h < 2; ++h) {
                        float a1 = h ? m1.y : m1.x;
                        float a2 = h ? m2.y : m2.x;
                        float bx = h ? xx.y : xx.x;
                        float by = h ? yy.y : yy.x;
                        float bz = h ? xy.y : xy.x;
                        float m11 = a1 * a1, m22 = a2 * a2, m12 = a1 * a2;
                        float s1 = bx - m11, s2 = by - m22, s12 = bz - m12;
                        float num = (2.f * m12 + C1) * (2.f * s12 + C2);
                        float den = (m11 + m22 + C1) * (s1 + s2 + C2);
                        acc = fmaf(num, __builtin_amdgcn_rcpf(den), acc);
                    }
                }

                // --- write next row into the other buffer, then sync ---
                if (jn < NI) {
                    sb[nxt][0][0][tid + 3] = __floats2half2_rn(nxv.x, nxv.y);
                    sb[nxt][0][1][tid + 3] = __floats2half2_rn(nxv.y, nxn);
                    sb[nxt][1][0][tid + 3] = __floats2half2_rn(nyv.x, nyv.y);
                    sb[nxt][1][1][tid + 3] = __floats2half2_rn(nyv.y, nyn);
                    if (tid == 0) {
                        sb[nxt][0][1][2] = __floats2half2_rn(0.f, nxv.x);
                        sb[nxt][1][1][2] = __floats2half2_rn(0.f, nyv.x);
                    }
                }
                __syncthreads();
            }
        }
    }

    // ---- block reduction ----
    #pragma unroll
    for (int off = 32; off > 0; off >>= 1)
        acc += __shfl_down(acc, off, 64);

    __shared__ float wsum[4];
    const int lane = tid & 63, wid = tid >> 6;
    if (lane == 0) wsum[wid] = acc;
    __syncthreads();
    if (tid == 0)
        partial[bid] = wsum[0] + wsum[1] + wsum[2] + wsum[3];
}

__global__ __launch_bounds__(256) void ssim_reduce_kernel(
    const float* __restrict__ partial, float* __restrict__ out)
{
    const int tid = threadIdx.x;
    double s = 0.0;
    for (int i = tid; i < NBLOCKS; i += 256) s += (double)partial[i];
    __shared__ double sd[256];
    sd[tid] = s;
    __syncthreads();
    for (int off = 128; off > 0; off >>= 1) {
        if (tid < off) sd[tid] += sd[tid + off];
        __syncthreads();
    }
    if (tid == 0) out[0] = (float)(1.0 - sd[0] / NPIXEL);
}

extern "C" void kernel_launch(void* const* d_in, const int* in_sizes, int n_in,
                              void* d_out, int out_size, void* d_ws, size_t ws_size,
                              hipStream_t stream) {
    const float* X = (const float*)d_in[0];
    const float* Y = (const float*)d_in[1];
    float* partial = (float*)d_ws;   // NBLOCKS floats = 3 KiB
    float* out = (float*)d_out;

    ssim_pk_kernel<<<NBLOCKS, 256, 0, stream>>>(X, Y, partial);
    ssim_reduce_kernel<<<1, 256, 0, stream>>>(partial, out);
}